// Round 3
// baseline (5103.485 us; speedup 1.0000x reference)
//
#include <hip/hip_runtime.h>

// ---------------------------------------------------------------------------
// MobileViTBlockv2 fused pipeline, fp32, workspace-lean (~195 MB).
// Shapes: B=32, C=128, H=W=64, D=256, FF=512, NL=2, PH=PW=2
// p layout: (B, D, P=4, N=1024), channel stride S=4096 per batch.
// Linear-attention trick: ctx = W_k @ t + b_k with t_c = sum_n LN(p)[c,n]*s_n,
// so k is never materialized. v and FFN-h are computed per-pp slice into a
// shared 64 MB scratch buffer (also reused as the dwconv output).
// ---------------------------------------------------------------------------

#define TB 256
#define NT 32
#define KC 128

constexpr int Bc = 32, Cc = 128, Dc = 256, FFc = 512;
constexpr int NNc = 1024, Sc = 4096;
constexpr float EPSc = 1e-5f;

enum InMode  { IN_PATCH, IN_LN, IN_RELUCTX, IN_PLAIN };
enum OutMode { OUT_STORE, OUT_ADD, OUT_LRELU, OUT_FOLDBN };

// ---- depthwise 3x3 conv + BN1 + leaky_relu(0.1) ---------------------------
__global__ __launch_bounds__(256) void k_dwconv(
    const float* __restrict__ x, const float* __restrict__ dww,
    const float* __restrict__ g, const float* __restrict__ bb,
    const float* __restrict__ mm, const float* __restrict__ vv,
    float* __restrict__ y1)
{
  int idx = blockIdx.x * 256 + threadIdx.x;            // (b*C+c)*S + h*64 + w
  int w = idx & 63, h = (idx >> 6) & 63, c = (idx >> 12) & 127;
  const float* xb = x + (size_t)(idx >> 12) * Sc;
  const float* wp = dww + c * 9;
  float acc = 0.f;
  #pragma unroll
  for (int kh = 0; kh < 3; ++kh) {
    int hh = h + kh - 1;
    if (hh < 0 || hh > 63) continue;
    #pragma unroll
    for (int kw = 0; kw < 3; ++kw) {
      int ww = w + kw - 1;
      if (ww < 0 || ww > 63) continue;
      acc += xb[hh * 64 + ww] * wp[kh * 3 + kw];
    }
  }
  float sc  = g[c] * rsqrtf(vv[c] + EPSc);
  float val = (acc - mm[c]) * sc + bb[c];
  y1[idx] = val > 0.f ? val : 0.1f * val;
}

// ---- per-position LN stats over D (channel-first layernorm) ---------------
__global__ __launch_bounds__(256) void k_lnstats(
    const float* __restrict__ p, float* __restrict__ mean_, float* __restrict__ rstd_)
{
  int pos = blockIdx.x * 256 + threadIdx.x;            // pos = b*S + s
  int b = pos >> 12, s = pos & 4095;
  const float* base = p + (size_t)b * Dc * Sc + s;
  float sum = 0.f, sq = 0.f;
  for (int d = 0; d < Dc; ++d) {
    float v = base[(size_t)d * Sc];
    sum += v; sq += v * v;
  }
  float m   = sum * (1.f / Dc);
  float var = sq * (1.f / Dc) - m * m;
  mean_[pos] = m;
  rstd_[pos] = rsqrtf(fmaxf(var, 0.f) + EPSc);
}

// ---- fused q-projection + softmax + t-pass, one block per (b, pp) ---------
// q_n = rs_n*(sum_d p[d,n]*wq_d*g_d) - m_n*rs_n*s1 + s2   (LN folded into wq)
// s = softmax(q);  u_n = rs_n*s_n;  U = sum m_n*u_n
// t_c = g_c*(sum_n p[c,n]*u_n - U) + b_c
__global__ __launch_bounds__(256) void k_attn_stats(
    const float* __restrict__ p, const float* __restrict__ mean_,
    const float* __restrict__ rstd_, const float* __restrict__ lng,
    const float* __restrict__ lnb, const float* __restrict__ wq,
    const float* __restrict__ qb, float* __restrict__ tb)
{
  int bp = blockIdx.x, b = bp >> 2, pp = bp & 3;
  int t = threadIdx.x, wave = t >> 6, lane = t & 63;
  __shared__ float wg[256], u[1024];
  __shared__ float r1[4], r2[4], r3[4], r4[4];

  float wqt = wq[t], gv = lng[t], bv = lnb[t];
  wg[t] = wqt * gv;
  float p1 = wqt * gv, p2 = wqt * bv;
  #pragma unroll
  for (int off = 32; off > 0; off >>= 1) {
    p1 += __shfl_xor(p1, off);
    p2 += __shfl_xor(p2, off);
  }
  if (lane == 0) { r1[wave] = p1; r2[wave] = p2; }
  __syncthreads();
  float s1 = r1[0] + r1[1] + r1[2] + r1[3];
  float s2 = r2[0] + r2[1] + r2[2] + r2[3] + qb[0];

  const float* pb = p + (size_t)b * Dc * Sc + pp * NNc;
  float m_r[4], rs_r[4], acc[4] = {0.f, 0.f, 0.f, 0.f};
  #pragma unroll
  for (int i = 0; i < 4; ++i) {
    int pos = b * Sc + pp * NNc + t + i * 256;
    m_r[i] = mean_[pos]; rs_r[i] = rstd_[pos];
  }
  for (int d = 0; d < Dc; ++d) {
    float wd = wg[d];
    const float* row = pb + (size_t)d * Sc;
    #pragma unroll
    for (int i = 0; i < 4; ++i) acc[i] += row[t + i * 256] * wd;
  }
  float q[4], mx = -3.4e38f;
  #pragma unroll
  for (int i = 0; i < 4; ++i) {
    q[i] = rs_r[i] * acc[i] - m_r[i] * rs_r[i] * s1 + s2;
    mx = fmaxf(mx, q[i]);
  }
  #pragma unroll
  for (int off = 32; off > 0; off >>= 1) mx = fmaxf(mx, __shfl_xor(mx, off));
  if (lane == 0) r3[wave] = mx;
  __syncthreads();
  mx = fmaxf(fmaxf(r3[0], r3[1]), fmaxf(r3[2], r3[3]));
  float sum = 0.f;
  #pragma unroll
  for (int i = 0; i < 4; ++i) { q[i] = __expf(q[i] - mx); sum += q[i]; }
  #pragma unroll
  for (int off = 32; off > 0; off >>= 1) sum += __shfl_xor(sum, off);
  if (lane == 0) r4[wave] = sum;
  __syncthreads();
  float inv = 1.f / (r4[0] + r4[1] + r4[2] + r4[3]);
  float pU = 0.f;
  #pragma unroll
  for (int i = 0; i < 4; ++i) {
    float s = q[i] * inv;
    int n = t + i * 256;
    float un = rs_r[i] * s;
    u[n] = un;
    pU += m_r[i] * un;
  }
  #pragma unroll
  for (int off = 32; off > 0; off >>= 1) pU += __shfl_xor(pU, off);
  if (lane == 0) r3[wave] = pU;
  __syncthreads();
  float U = r3[0] + r3[1] + r3[2] + r3[3];

  for (int c = wave; c < Dc; c += 4) {
    const float* row = pb + (size_t)c * Sc;
    float sm = 0.f;
    #pragma unroll
    for (int j = 0; j < 16; ++j) { int n = lane + 64 * j; sm += row[n] * u[n]; }
    #pragma unroll
    for (int off = 32; off > 0; off >>= 1) sm += __shfl_xor(sm, off);
    if (lane == 0) tb[(size_t)bp * 256 + c] = lng[c] * (sm - U) + lnb[c];
  }
}

// ---- ctx[b,d,pp] = wk_row_d . t[b,pp,:] + bk_d ----------------------------
__global__ __launch_bounds__(256) void k_ctx2(
    const float* __restrict__ tb, const float* __restrict__ wk,
    const float* __restrict__ bk, float* __restrict__ ctxb)
{
  int b = blockIdx.x, d = threadIdx.x;
  __shared__ float ts[4][256];
  for (int i = threadIdx.x; i < 1024; i += 256) ts[i >> 8][i & 255] = tb[(size_t)b * 1024 + i];
  __syncthreads();
  const float* wrow = wk + (size_t)d * 256;
  float bkd = bk[d];
  float accp[4] = {0.f, 0.f, 0.f, 0.f};
  for (int c = 0; c < 256; c += 4) {
    float4 wv = *reinterpret_cast<const float4*>(wrow + c);
    #pragma unroll
    for (int pp = 0; pp < 4; ++pp)
      accp[pp] += wv.x * ts[pp][c] + wv.y * ts[pp][c + 1]
                + wv.z * ts[pp][c + 2] + wv.w * ts[pp][c + 3];
  }
  #pragma unroll
  for (int pp = 0; pp < 4; ++pp)
    ctxb[((size_t)(b * 256 + d)) * 4 + pp] = accp[pp] + bkd;
}

// ---- BN2 scale/shift precompute -------------------------------------------
__global__ void k_bn2pre(const float* __restrict__ g, const float* __restrict__ bb,
                         const float* __restrict__ mm, const float* __restrict__ vv,
                         float* __restrict__ sc, float* __restrict__ sh)
{
  int c = threadIdx.x;
  if (c < Cc) {
    float s = g[c] * rsqrtf(vv[c] + EPSc);
    sc[c] = s;
    sh[c] = bb[c] - mm[c] * s;
  }
}

// ---------------------------------------------------------------------------
// Generic channels-first 1x1-conv GEMM. One block: (b, pp, 32-col n-tile,
// 256-row o-tile). Input tile staged in LDS with optional fused transform.
// ctx_s / m_s / rs_s are written ONCE before the k-loop (all writes precede
// the loop-top __syncthreads(), never rewritten -> no cross-wave race).
// ---------------------------------------------------------------------------
template<int KTOT, int NOUT, int SRCCH, int SRCOFF, int SSTR, bool SPP,
         int DSTR, bool DPP, InMode IM, OutMode OM, bool FULLY>
__global__ __launch_bounds__(256) void k_gemm(
    const float* __restrict__ src,
    const float* __restrict__ mean_, const float* __restrict__ rstd_,
    const float* __restrict__ lng, const float* __restrict__ lnb,
    const float* __restrict__ ctxp,
    const float* __restrict__ w, const float* __restrict__ wb,
    const float* __restrict__ bnsc, const float* __restrict__ bnsh,
    float* __restrict__ dst, int ppArg)
{
  int nt = blockIdx.x;
  int pp, ot;
  if (FULLY) { pp = blockIdx.y & 3; ot = blockIdx.y >> 2; }
  else       { pp = ppArg;          ot = blockIdx.y; }
  int b  = blockIdx.z;
  int t  = threadIdx.x;
  int n0 = nt * NT;
  int o  = ot * TB + t;
  int ph = pp >> 1, pw = pp & 1;

  __shared__ float At[KC][NT];
  __shared__ float ctx_s[Dc];          // full depth, loaded once
  __shared__ float m_s[NT], rs_s[NT];

  if (IM == IN_LN) {
    if (t < NT) {
      int pos = b * Sc + pp * NNc + n0 + t;
      m_s[t]  = mean_[pos];
      rs_s[t] = rstd_[pos];
    }
  }
  if (IM == IN_RELUCTX) {
    // KTOT==256 for this mode; one write per thread, before first sync.
    ctx_s[t] = ctxp[(size_t)(b * Dc + t) * 4 + pp];
  }

  float acc[NT];
  #pragma unroll
  for (int j = 0; j < NT; ++j) acc[j] = 0.f;

  for (int kc = 0; kc < KTOT; kc += KC) {
    __syncthreads();
    for (int i = t; i < KC * NT; i += TB) {
      int c = i >> 5, j = i & 31;
      float v;
      if (IM == IN_PATCH) {
        int n = n0 + j;
        int hh = 2 * (n >> 5) + ph, ww = 2 * (n & 31) + pw;
        v = src[((size_t)(b * SRCCH + kc + c)) * Sc + hh * 64 + ww];
      } else {
        size_t a = (size_t)(b * SRCCH + SRCOFF + kc + c) * SSTR + n0 + j;
        if (SPP) a += pp * NNc;
        v = src[a];
      }
      if (IM == IN_LN)      v = (v - m_s[j]) * rs_s[j] * lng[kc + c] + lnb[kc + c];
      if (IM == IN_RELUCTX) v = fmaxf(v, 0.f) * ctx_s[kc + c];
      At[c][j] = v;
    }
    __syncthreads();
    if (o < NOUT) {
      const float* wrow = w + (size_t)o * KTOT + kc;
      for (int c = 0; c < KC; c += 4) {
        float4 wv = *reinterpret_cast<const float4*>(wrow + c);
        #pragma unroll
        for (int j = 0; j < NT; ++j) acc[j] += wv.x * At[c][j];
        #pragma unroll
        for (int j = 0; j < NT; ++j) acc[j] += wv.y * At[c + 1][j];
        #pragma unroll
        for (int j = 0; j < NT; ++j) acc[j] += wv.z * At[c + 2][j];
        #pragma unroll
        for (int j = 0; j < NT; ++j) acc[j] += wv.w * At[c + 3][j];
      }
    }
  }

  if (o < NOUT) {
    if (OM == OUT_FOLDBN) {
      float scv = bnsc[o], shv = bnsh[o];
      #pragma unroll
      for (int j = 0; j < NT; ++j) {
        int n = n0 + j;
        int hh = 2 * (n >> 5) + ph, ww = 2 * (n & 31) + pw;
        dst[((size_t)(b * Cc + o)) * Sc + hh * 64 + ww] = acc[j] * scv + shv;
      }
    } else {
      float bv = wb[o];
      size_t doff = (size_t)(b * NOUT + o) * DSTR + n0;
      if (DPP) doff += pp * NNc;
      float* drow = dst + doff;
      #pragma unroll
      for (int j = 0; j < NT; ++j) {
        float v = acc[j] + bv;
        if (OM == OUT_LRELU) v = v > 0.f ? v : 0.1f * v;
        if (OM == OUT_ADD) drow[j] += v; else drow[j] = v;
      }
    }
  }
}

// ---------------------------------------------------------------------------
extern "C" void kernel_launch(void* const* d_in, const int* in_sizes, int n_in,
                              void* d_out, int out_size, void* d_ws, size_t ws_size,
                              hipStream_t stream)
{
  const float* x     = (const float*)d_in[0];
  const float* dw_w  = (const float*)d_in[1];
  const float* bn1_g = (const float*)d_in[2];
  const float* bn1_b = (const float*)d_in[3];
  const float* bn1_m = (const float*)d_in[4];
  const float* bn1_v = (const float*)d_in[5];
  const float* c1_w  = (const float*)d_in[6];
  const float* c1_b  = (const float*)d_in[7];
  const float* ln1_g = (const float*)d_in[8];
  const float* ln1_b = (const float*)d_in[9];
  const float* qkv_w = (const float*)d_in[10];
  const float* qkv_b = (const float*)d_in[11];
  const float* out_w = (const float*)d_in[12];
  const float* out_b = (const float*)d_in[13];
  const float* ln2_g = (const float*)d_in[14];
  const float* ln2_b = (const float*)d_in[15];
  const float* f1_w  = (const float*)d_in[16];
  const float* f1_b  = (const float*)d_in[17];
  const float* f2_w  = (const float*)d_in[18];
  const float* f2_b  = (const float*)d_in[19];
  const float* lnf_g = (const float*)d_in[20];
  const float* lnf_b = (const float*)d_in[21];
  const float* projw = (const float*)d_in[22];
  const float* bn2_g = (const float*)d_in[23];
  const float* bn2_b = (const float*)d_in[24];
  const float* bn2_m = (const float*)d_in[25];
  const float* bn2_v = (const float*)d_in[26];
  float* out = (float*)d_out;

  // Workspace (~195 MB total):
  float* ws    = (float*)d_ws;
  float* p     = ws;                                   // B*D*S = 33,554,432 fl
  float* sb    = p     + (size_t)Bc * Dc * Sc;         // 16,777,216 fl (y1 / v-slice / h-slice)
  float* meanb = sb    + (size_t)Bc * FFc * NNc;       // 131,072
  float* rstdb = meanb + (size_t)Bc * Sc;              // 131,072
  float* tb    = rstdb + (size_t)Bc * Sc;              // 32,768
  float* ctxb  = tb    + (size_t)Bc * 4 * Dc;          // 32,768
  float* bnscb = ctxb  + (size_t)Bc * Dc * 4;          // 128
  float* bnshb = bnscb + Cc;                           // 128

  // 1) dwconv + BN1 + lrelu  (into sb)
  k_dwconv<<<(Bc * Cc * Sc) / 256, 256, 0, stream>>>(x, dw_w, bn1_g, bn1_b, bn1_m, bn1_v, sb);

  // 2) conv1x1 C->D fused with unfold (writes p layout directly)
  k_gemm<128, 256, 128, 0, Sc, true, Sc, true, IN_PATCH, OUT_STORE, true>
      <<<dim3(32, 4, 32), 256, 0, stream>>>(
      sb, nullptr, nullptr, nullptr, nullptr, nullptr, c1_w, c1_b, nullptr, nullptr, p, 0);

  for (int l = 0; l < 2; ++l) {
    const float* g1 = ln1_g + l * Dc, *b1 = ln1_b + l * Dc;
    const float* g2 = ln2_g + l * Dc, *b2 = ln2_b + l * Dc;
    const float* wq = qkv_w + (size_t)l * 513 * Dc;              // row 0
    const float* wk = qkv_w + ((size_t)l * 513 + 1) * Dc;        // rows 1..256
    const float* wv = qkv_w + ((size_t)l * 513 + 257) * Dc;      // rows 257..512
    const float* bq = qkv_b + l * 513;
    const float* bk = qkv_b + l * 513 + 1;
    const float* bv = qkv_b + l * 513 + 257;

    // 3) LN1 stats
    k_lnstats<<<512, 256, 0, stream>>>(p, meanb, rstdb);
    // 4) fused q + softmax + t
    k_attn_stats<<<Bc * 4, 256, 0, stream>>>(p, meanb, rstdb, g1, b1, wq, bq, tb);
    // 5) ctx = W_k @ t + b_k
    k_ctx2<<<Bc, 256, 0, stream>>>(tb, wk, bk, ctxb);
    // 6) per-pp: v = W_v @ LN1(p) + b_v  (slice into sb), then
    //            p += W_out @ (relu(v)*ctx) + b_out
    for (int pp = 0; pp < 4; ++pp) {
      k_gemm<256, 256, 256, 0, Sc, true, NNc, false, IN_LN, OUT_STORE, false>
          <<<dim3(32, 1, 32), 256, 0, stream>>>(
          p, meanb, rstdb, g1, b1, nullptr, wv, bv, nullptr, nullptr, sb, pp);
      k_gemm<256, 256, 256, 0, NNc, false, Sc, true, IN_RELUCTX, OUT_ADD, false>
          <<<dim3(32, 1, 32), 256, 0, stream>>>(
          sb, nullptr, nullptr, nullptr, nullptr, ctxb,
          out_w + (size_t)l * Dc * Dc, out_b + l * Dc, nullptr, nullptr, p, pp);
    }
    // 7) LN2 stats
    k_lnstats<<<512, 256, 0, stream>>>(p, meanb, rstdb);
    // 8) per-pp FFN: h = lrelu(W1 @ LN2(p) + b1), p += W2 @ h + b2
    for (int pp = 0; pp < 4; ++pp) {
      k_gemm<256, 512, 256, 0, Sc, true, NNc, false, IN_LN, OUT_LRELU, false>
          <<<dim3(32, 2, 32), 256, 0, stream>>>(
          p, meanb, rstdb, g2, b2, nullptr,
          f1_w + (size_t)l * FFc * Dc, f1_b + l * FFc, nullptr, nullptr, sb, pp);
      k_gemm<512, 256, 512, 0, NNc, false, Sc, true, IN_PLAIN, OUT_ADD, false>
          <<<dim3(32, 1, 32), 256, 0, stream>>>(
          sb, nullptr, nullptr, nullptr, nullptr, nullptr,
          f2_w + (size_t)l * Dc * FFc, f2_b + l * Dc, nullptr, nullptr, p, pp);
    }
  }

  // 9) final LN stats + BN2 precompute
  k_lnstats<<<512, 256, 0, stream>>>(p, meanb, rstdb);
  k_bn2pre<<<1, 128, 0, stream>>>(bn2_g, bn2_b, bn2_m, bn2_v, bnscb, bnshb);
  // 10) out = BN2(proj @ LNf(p)) fused with fold, direct to d_out
  k_gemm<256, 128, 256, 0, Sc, true, Sc, true, IN_LN, OUT_FOLDBN, true>
      <<<dim3(32, 4, 32), 256, 0, stream>>>(
      p, meanb, rstdb, lnf_g, lnf_b, nullptr, projw, nullptr, bnscb, bnshb, out, 0);
}

// Round 5
// 1249.992 us; speedup vs baseline: 4.0828x; 4.0828x over previous
//
#include <hip/hip_runtime.h>

// ---------------------------------------------------------------------------
// MobileViTBlockv2 fused pipeline — bf16 MFMA GEMMs, fp32 everywhere else.
// B=32, C=128, H=W=64, D=256, FF=512, NL=2, PH=PW=2
// p layout: (B, D, P=4, N=1024) fp32, channel stride 4096 per batch.
// Weights preconverted to MFMA A-fragment order bf16. Activations staged to
// LDS transposed (stride-40 ushort rows) with fused LN/convert. v/h/y1 bf16.
// ---------------------------------------------------------------------------

typedef short  bh8 __attribute__((ext_vector_type(8)));   // 8 bf16 = 4 VGPR
typedef float  f4  __attribute__((ext_vector_type(4)));   // MFMA acc

constexpr int Bc = 32, Cc = 128, Dc = 256, FFc = 512;
constexpr int NNc = 1024, Sc = 4096;
constexpr float EPSc = 1e-5f;

enum SrcMode { S_LNF32, S_BF16 };
enum OutMode { O_STOREF32, O_ADDF32, O_RELUCTX_BF16, O_LRELU_BF16, O_FOLDBN };

__device__ __forceinline__ unsigned short f2bf(float f) {
  union { float f; unsigned int u; } v; v.f = f;
  unsigned int u = v.u + 0x7FFFu + ((v.u >> 16) & 1u);
  return (unsigned short)(u >> 16);
}

// ---- weight fp32 -> bf16 MFMA-fragment-order ------------------------------
// element (m,k) -> ((tk*(M/16)+tm)*64 + lane)*8 + j ; lane=((k>>3)&3)<<4|(m&15)
__global__ __launch_bounds__(256) void k_wconv(
    const float* __restrict__ w, unsigned short* __restrict__ dst,
    int total, int klog2)
{
  int idx = blockIdx.x * 256 + threadIdx.x;
  if (idx >= total) return;
  int K = 1 << klog2;
  int m = idx >> klog2, k = idx & (K - 1);
  int Mt = total >> klog2;          // M
  size_t a = ((size_t)((k >> 5) * (Mt >> 4) + (m >> 4)) * 64
              + (((k >> 3) & 3) << 4) + (m & 15)) * 8 + (k & 7);
  dst[a] = f2bf(w[idx]);
}

// ---- depthwise 3x3 conv + BN1 + lrelu, bf16 out in patch-split layout -----
__global__ __launch_bounds__(256) void k_dwconv(
    const float* __restrict__ x, const float* __restrict__ dww,
    const float* __restrict__ g, const float* __restrict__ bb,
    const float* __restrict__ mm, const float* __restrict__ vv,
    unsigned short* __restrict__ y1)
{
  int idx = blockIdx.x * 256 + threadIdx.x;            // (b*C+c)*S + h*64 + w
  int w = idx & 63, h = (idx >> 6) & 63, c = (idx >> 12) & 127;
  const float* xb = x + (size_t)(idx >> 12) * Sc;
  const float* wp = dww + c * 9;
  float acc = 0.f;
  #pragma unroll
  for (int kh = 0; kh < 3; ++kh) {
    int hh = h + kh - 1;
    if (hh < 0 || hh > 63) continue;
    #pragma unroll
    for (int kw = 0; kw < 3; ++kw) {
      int ww = w + kw - 1;
      if (ww < 0 || ww > 63) continue;
      acc += xb[hh * 64 + ww] * wp[kh * 3 + kw];
    }
  }
  float sc  = g[c] * rsqrtf(vv[c] + EPSc);
  float val = (acc - mm[c]) * sc + bb[c];
  val = val > 0.f ? val : 0.1f * val;
  int pp = (h & 1) * 2 + (w & 1);
  int n  = (h >> 1) * 32 + (w >> 1);
  y1[(size_t)(idx >> 12) * Sc + pp * NNc + n] = f2bf(val);
}

// ---- LN stats over D, optionally fused q-dot ------------------------------
template<bool QD>
__global__ __launch_bounds__(256) void k_lnstats(
    const float* __restrict__ p, const float* __restrict__ wgq,
    float* __restrict__ mean_, float* __restrict__ rstd_, float* __restrict__ qdot)
{
  __shared__ float wg_s[256];
  int t = threadIdx.x;
  if (QD) { wg_s[t] = wgq[t]; __syncthreads(); }
  int pos = blockIdx.x * 256 + t;
  int b = pos >> 12, s = pos & 4095;
  const float* base = p + (size_t)b * Dc * Sc + s;
  float sum = 0.f, sq = 0.f, qa = 0.f;
  for (int d = 0; d < Dc; ++d) {
    float v = base[(size_t)d * Sc];
    sum += v; sq += v * v;
    if (QD) qa += v * wg_s[d];
  }
  float m   = sum * (1.f / Dc);
  float var = sq * (1.f / Dc) - m * m;
  mean_[pos] = m;
  rstd_[pos] = rsqrtf(fmaxf(var, 0.f) + EPSc);
  if (QD) qdot[pos] = qa;
}

// ---- per-layer prep: wgq = wq*g, s1 = sum(wq*g), s2 = sum(wq*b)+bq --------
__global__ void k_prep(const float* __restrict__ wq, const float* __restrict__ lng,
                       const float* __restrict__ lnb, const float* __restrict__ qb,
                       float* __restrict__ wgq, float* __restrict__ scal)
{
  int t = threadIdx.x, lane = t & 63, wv = t >> 6;
  float w = wq[t];
  float a = w * lng[t], c2 = w * lnb[t];
  wgq[t] = a;
  __shared__ float ra[4], rb[4];
  #pragma unroll
  for (int off = 32; off > 0; off >>= 1) { a += __shfl_xor(a, off); c2 += __shfl_xor(c2, off); }
  if (lane == 0) { ra[wv] = a; rb[wv] = c2; }
  __syncthreads();
  if (t == 0) {
    scal[0] = ra[0] + ra[1] + ra[2] + ra[3];
    scal[1] = rb[0] + rb[1] + rb[2] + rb[3] + qb[0];
  }
}

// ---- softmax over N from qdot/stats; emits u[n]=rs*s and U=sum(m*u) -------
__global__ __launch_bounds__(256) void k_softmax2(
    const float* __restrict__ qdot, const float* __restrict__ mean_,
    const float* __restrict__ rstd_, const float* __restrict__ scal,
    float* __restrict__ ub, float* __restrict__ Ub)
{
  int bp = blockIdx.x, b = bp >> 2, pp = bp & 3;
  int t = threadIdx.x, lane = t & 63, wv = t >> 6;
  __shared__ float r3[4], r4[4];
  float s1 = scal[0], s2 = scal[1];
  int pos0 = b * Sc + pp * NNc;
  float q[4], m_r[4], rs_r[4];
  float mx = -3.4e38f;
  #pragma unroll
  for (int i = 0; i < 4; ++i) {
    int pos = pos0 + t + i * 256;
    m_r[i] = mean_[pos]; rs_r[i] = rstd_[pos];
    q[i] = rs_r[i] * qdot[pos] - m_r[i] * rs_r[i] * s1 + s2;
    mx = fmaxf(mx, q[i]);
  }
  #pragma unroll
  for (int off = 32; off > 0; off >>= 1) mx = fmaxf(mx, __shfl_xor(mx, off));
  if (lane == 0) r3[wv] = mx;
  __syncthreads();
  mx = fmaxf(fmaxf(r3[0], r3[1]), fmaxf(r3[2], r3[3]));
  float sum = 0.f;
  #pragma unroll
  for (int i = 0; i < 4; ++i) { q[i] = __expf(q[i] - mx); sum += q[i]; }
  #pragma unroll
  for (int off = 32; off > 0; off >>= 1) sum += __shfl_xor(sum, off);
  if (lane == 0) r4[wv] = sum;
  __syncthreads();
  float inv = 1.f / (r4[0] + r4[1] + r4[2] + r4[3]);
  float pU = 0.f;
  #pragma unroll
  for (int i = 0; i < 4; ++i) {
    float un = rs_r[i] * q[i] * inv;
    ub[(size_t)bp * NNc + t + i * 256] = un;
    pU += m_r[i] * un;
  }
  #pragma unroll
  for (int off = 32; off > 0; off >>= 1) pU += __shfl_xor(pU, off);
  if (lane == 0) r3[wv] = pU;
  __syncthreads();
  if (t == 0) Ub[bp] = r3[0] + r3[1] + r3[2] + r3[3];
}

// ---- t_c = g_c*(sum_n p[c,n]*u[n] - U) + b_c ------------------------------
__global__ __launch_bounds__(256) void k_tpass(
    const float* __restrict__ p, const float* __restrict__ ub,
    const float* __restrict__ Ub, const float* __restrict__ lng,
    const float* __restrict__ lnb, float* __restrict__ tb)
{
  int cs = blockIdx.x, pp = blockIdx.y, b = blockIdx.z;
  int bp = b * 4 + pp;
  int t = threadIdx.x, lane = t & 63, wv = t >> 6;
  __shared__ float u_s[1024];
  for (int i = t; i < 1024; i += 256) u_s[i] = ub[(size_t)bp * NNc + i];
  __syncthreads();
  float U = Ub[bp];
  const float* pb = p + (size_t)b * Dc * Sc + pp * NNc;
  for (int i = 0; i < 16; ++i) {
    int c = cs * 64 + wv * 16 + i;
    const float* row = pb + (size_t)c * Sc;
    float sm = 0.f;
    #pragma unroll
    for (int j = 0; j < 16; ++j) { int n = lane + 64 * j; sm += row[n] * u_s[n]; }
    #pragma unroll
    for (int off = 32; off > 0; off >>= 1) sm += __shfl_xor(sm, off);
    if (lane == 0) tb[(size_t)bp * Dc + c] = lng[c] * (sm - U) + lnb[c];
  }
}

// ---- ctx[b,d,pp] = wk_row_d . t[b,pp,:] + bk_d ----------------------------
__global__ __launch_bounds__(256) void k_ctx2(
    const float* __restrict__ tb, const float* __restrict__ wk,
    const float* __restrict__ bk, float* __restrict__ ctxb)
{
  int b = blockIdx.x, d = threadIdx.x;
  __shared__ float ts[4][256];
  for (int i = threadIdx.x; i < 1024; i += 256) ts[i >> 8][i & 255] = tb[(size_t)b * 1024 + i];
  __syncthreads();
  const float* wrow = wk + (size_t)d * 256;
  float bkd = bk[d];
  float accp[4] = {0.f, 0.f, 0.f, 0.f};
  for (int c = 0; c < 256; c += 4) {
    float4 wv = *reinterpret_cast<const float4*>(wrow + c);
    #pragma unroll
    for (int pp = 0; pp < 4; ++pp)
      accp[pp] += wv.x * ts[pp][c] + wv.y * ts[pp][c + 1]
                + wv.z * ts[pp][c + 2] + wv.w * ts[pp][c + 3];
  }
  #pragma unroll
  for (int pp = 0; pp < 4; ++pp)
    ctxb[((size_t)(b * 256 + d)) * 4 + pp] = accp[pp] + bkd;
}

__global__ void k_bn2pre(const float* __restrict__ g, const float* __restrict__ bb,
                         const float* __restrict__ mm, const float* __restrict__ vv,
                         float* __restrict__ sc, float* __restrict__ sh)
{
  int c = threadIdx.x;
  if (c < Cc) {
    float s = g[c] * rsqrtf(vv[c] + EPSc);
    sc[c] = s;
    sh[c] = bb[c] - mm[c] * s;
  }
}

// ---------------------------------------------------------------------------
// MFMA GEMM: block = 128 out-rows x 128 n-cols for one (b, pp). 4 waves,
// each wave a 64x64 quadrant = 4x4 tiles of 16x16x32 MFMA. A (weights) read
// directly from global in fragment order; B (activations) staged to LDS
// transposed [n][k] (stride 40 ushorts = 80 B, 16B-aligned) with fused
// LN-transform / bf16 convert.
// ---------------------------------------------------------------------------
template<int KTOT, int MTOT, int SRCCH, int SSTR, bool SPP, int DSTR, bool DPP,
         SrcMode SM, OutMode OM, bool FULLPP>
__global__ __launch_bounds__(256) void k_mm(
    const void* __restrict__ src,
    const float* __restrict__ mean_, const float* __restrict__ rstd_,
    const float* __restrict__ lng, const float* __restrict__ lnb,
    const unsigned short* __restrict__ wf, const float* __restrict__ bias,
    const float* __restrict__ ctxp, const float* __restrict__ bnsc,
    const float* __restrict__ bnsh, void* __restrict__ dst, int ppArg)
{
  int t = threadIdx.x;
  int wv = t >> 6, lane = t & 63;
  int wm = wv & 1, wn = wv >> 1;
  int q = lane >> 4, ln16 = lane & 15;
  int nb = blockIdx.x, b = blockIdx.z;
  int pp, mb;
  if (FULLPP) { pp = blockIdx.y & 3; mb = blockIdx.y >> 2; }
  else        { pp = ppArg;          mb = blockIdx.y; }
  int n0  = nb * 128;
  int MB0 = mb * 128;

  __shared__ unsigned int Alds[128 * 20];   // [n][kpair], stride 20 uints
  __shared__ float m_s[128], rs_s[128];

  if (SM == S_LNF32 && t < 128) {
    int pos = b * Sc + pp * NNc + n0 + t;
    m_s[t]  = mean_[pos];
    rs_s[t] = rstd_[pos];
  }

  f4 acc[4][4];
  #pragma unroll
  for (int i = 0; i < 4; ++i)
    #pragma unroll
    for (int j = 0; j < 4; ++j)
      acc[i][j] = (f4){0.f, 0.f, 0.f, 0.f};

  size_t sbase = (size_t)b * SRCCH * SSTR + (SPP ? pp * NNc : 0) + n0;
  int mtb = (MB0 >> 4) + wm * 4;

  for (int kc = 0; kc < KTOT; kc += 32) {
    // A-fragments straight from global (fragment-order, coalesced per wave)
    bh8 aw[4];
    #pragma unroll
    for (int tm = 0; tm < 4; ++tm) {
      size_t off = ((size_t)((kc >> 5) * (MTOT >> 4) + mtb + tm) * 64 + lane) * 8;
      aw[tm] = *(const bh8*)(wf + off);
    }
    __syncthreads();
    // stage B chunk (32 k x 128 n), transposed, transformed, bf16-packed
    #pragma unroll
    for (int it = 0; it < 8; ++it) {
      int n_l = (t & 63) + (it & 1) * 64;
      int kp  = (t >> 6) + (it >> 1) * 4;
      int k0  = kc + kp * 2;
      unsigned int pk;
      if (SM == S_LNF32) {
        const float* sp = (const float*)src;
        float a0 = sp[sbase + (size_t)k0 * SSTR + n_l];
        float a1 = sp[sbase + (size_t)(k0 + 1) * SSTR + n_l];
        float ms = m_s[n_l], rs = rs_s[n_l];
        a0 = (a0 - ms) * rs * lng[k0] + lnb[k0];
        a1 = (a1 - ms) * rs * lng[k0 + 1] + lnb[k0 + 1];
        pk = (unsigned int)f2bf(a0) | ((unsigned int)f2bf(a1) << 16);
      } else {
        const unsigned short* sp = (const unsigned short*)src;
        unsigned int u0 = sp[sbase + (size_t)k0 * SSTR + n_l];
        unsigned int u1 = sp[sbase + (size_t)(k0 + 1) * SSTR + n_l];
        pk = u0 | (u1 << 16);
      }
      Alds[n_l * 20 + kp] = pk;
    }
    __syncthreads();
    // compute
    const unsigned short* al = (const unsigned short*)Alds;
    #pragma unroll
    for (int tn = 0; tn < 4; ++tn) {
      int nrow = wn * 64 + tn * 16 + ln16;
      bh8 bwf = *(const bh8*)(al + nrow * 40 + q * 8);
      #pragma unroll
      for (int tm = 0; tm < 4; ++tm)
        acc[tm][tn] = __builtin_amdgcn_mfma_f32_16x16x32_bf16(aw[tm], bwf, acc[tm][tn], 0, 0, 0);
    }
  }

  // epilogue
  #pragma unroll
  for (int tm = 0; tm < 4; ++tm) {
    #pragma unroll
    for (int r = 0; r < 4; ++r) {
      int row = MB0 + wm * 64 + tm * 16 + q * 4 + r;
      float bv = 0.f, cx = 0.f, scv = 0.f, shv = 0.f;
      if (OM == O_FOLDBN) { scv = bnsc[row]; shv = bnsh[row]; }
      else                { bv = bias[row]; }
      if (OM == O_RELUCTX_BF16) cx = ctxp[((size_t)(b * Dc + row)) * 4 + pp];
      #pragma unroll
      for (int tn = 0; tn < 4; ++tn) {
        int col = n0 + wn * 64 + tn * 16 + ln16;
        float v = acc[tm][tn][r];
        if (OM == O_FOLDBN) {
          int hh = 2 * (col >> 5) + (pp >> 1), ww = 2 * (col & 31) + (pp & 1);
          ((float*)dst)[((size_t)(b * Cc + row)) * Sc + hh * 64 + ww] = v * scv + shv;
        } else {
          v += bv;
          size_t da = (size_t)(b * MTOT + row) * DSTR + (DPP ? pp * NNc : 0) + col;
          if (OM == O_STOREF32)      ((float*)dst)[da] = v;
          else if (OM == O_ADDF32)   ((float*)dst)[da] += v;
          else if (OM == O_LRELU_BF16) {
            v = v > 0.f ? v : 0.1f * v;
            ((unsigned short*)dst)[da] = f2bf(v);
          } else { // O_RELUCTX_BF16
            v = fmaxf(v, 0.f) * cx;
            ((unsigned short*)dst)[da] = f2bf(v);
          }
        }
      }
    }
  }
}

// ---------------------------------------------------------------------------
extern "C" void kernel_launch(void* const* d_in, const int* in_sizes, int n_in,
                              void* d_out, int out_size, void* d_ws, size_t ws_size,
                              hipStream_t stream)
{
  const float* x     = (const float*)d_in[0];
  const float* dw_w  = (const float*)d_in[1];
  const float* bn1_g = (const float*)d_in[2];
  const float* bn1_b = (const float*)d_in[3];
  const float* bn1_m = (const float*)d_in[4];
  const float* bn1_v = (const float*)d_in[5];
  const float* c1_w  = (const float*)d_in[6];
  const float* c1_b  = (const float*)d_in[7];
  const float* ln1_g = (const float*)d_in[8];
  const float* ln1_b = (const float*)d_in[9];
  const float* qkv_w = (const float*)d_in[10];
  const float* qkv_b = (const float*)d_in[11];
  const float* out_w = (const float*)d_in[12];
  const float* out_b = (const float*)d_in[13];
  const float* ln2_g = (const float*)d_in[14];
  const float* ln2_b = (const float*)d_in[15];
  const float* f1_w  = (const float*)d_in[16];
  const float* f1_b  = (const float*)d_in[17];
  const float* f2_w  = (const float*)d_in[18];
  const float* f2_b  = (const float*)d_in[19];
  const float* lnf_g = (const float*)d_in[20];
  const float* lnf_b = (const float*)d_in[21];
  const float* projw = (const float*)d_in[22];
  const float* bn2_g = (const float*)d_in[23];
  const float* bn2_b = (const float*)d_in[24];
  const float* bn2_m = (const float*)d_in[25];
  const float* bn2_v = (const float*)d_in[26];
  float* out = (float*)d_out;

  // ---- workspace carve-up (~206 MB) ----
  float* ws    = (float*)d_ws;
  float* p     = ws;                                       // 33,554,432 f
  float* reg   = p + (size_t)33554432;                     // 16,777,216 f shared region
  unsigned short* y1u = (unsigned short*)reg;              // 16.8M ushort (first half)
  unsigned short* vu  = (unsigned short*)reg;              // 33.5M ushort (all)
  unsigned short* hu  = (unsigned short*)reg;              // 16.8M ushort per-pp slice
  float* meanb = reg   + (size_t)16777216;                 // 131072
  float* rstdb = meanb + 131072;
  float* qdotb = rstdb + 131072;
  float* ub    = qdotb + 131072;
  float* Ub    = ub    + 131072;                           // 128
  float* tb    = Ub    + 128;                              // 32768
  float* ctxb  = tb    + 32768;                            // 32768
  float* wgq   = ctxb  + 32768;                            // 256
  float* scal  = wgq   + 256;                              // 16
  float* bnscb = scal  + 16;                               // 128
  float* bnshb = bnscb + 128;                              // 128
  unsigned short* wfb = (unsigned short*)(bnshb + 128);
  unsigned short* wf_c1   = wfb;                           // 32768
  unsigned short* wf_v0   = wfb + 32768;                   // per-l stride 393216
  // per l: v(65536), out(65536), f1(131072), f2(131072)
  unsigned short* wf_proj = wfb + 32768 + 2 * 393216;      // 32768

  // ---- weight conversion (10 small launches) ----
  k_wconv<<<(32768 + 255) / 256, 256, 0, stream>>>(c1_w, wf_c1, 256 * 128, 7);
  for (int l = 0; l < 2; ++l) {
    const float* wvp = qkv_w + ((size_t)l * 513 + 257) * Dc;
    unsigned short* base = wf_v0 + (size_t)l * 393216;
    k_wconv<<<(65536 + 255) / 256, 256, 0, stream>>>(wvp, base, 256 * 256, 8);
    k_wconv<<<(65536 + 255) / 256, 256, 0, stream>>>(out_w + (size_t)l * Dc * Dc, base + 65536, 256 * 256, 8);
    k_wconv<<<(131072 + 255) / 256, 256, 0, stream>>>(f1_w + (size_t)l * FFc * Dc, base + 131072, 512 * 256, 8);
    k_wconv<<<(131072 + 255) / 256, 256, 0, stream>>>(f2_w + (size_t)l * Dc * FFc, base + 262144, 256 * 512, 9);
  }
  k_wconv<<<(32768 + 255) / 256, 256, 0, stream>>>(projw, wf_proj, 128 * 256, 8);

  // ---- 1) dwconv + BN1 + lrelu -> y1 bf16 (patch layout) ----
  k_dwconv<<<(Bc * Cc * Sc) / 256, 256, 0, stream>>>(x, dw_w, bn1_g, bn1_b, bn1_m, bn1_v, y1u);

  // ---- 2) c1: p = W_c1 @ y1 + b ----
  k_mm<128, 256, 128, 4096, true, 4096, true, S_BF16, O_STOREF32, true>
      <<<dim3(8, 8, 32), 256, 0, stream>>>(
      y1u, nullptr, nullptr, nullptr, nullptr, wf_c1, c1_b,
      nullptr, nullptr, nullptr, p, 0);

  for (int l = 0; l < 2; ++l) {
    const float* g1 = ln1_g + l * Dc; const float* b1 = ln1_b + l * Dc;
    const float* g2 = ln2_g + l * Dc; const float* b2 = ln2_b + l * Dc;
    const float* wq = qkv_w + (size_t)l * 513 * Dc;
    const float* wk = qkv_w + ((size_t)l * 513 + 1) * Dc;
    const float* bq = qkv_b + l * 513;
    const float* bk = qkv_b + l * 513 + 1;
    const float* bvv = qkv_b + l * 513 + 257;
    unsigned short* wbase = wf_v0 + (size_t)l * 393216;

    k_prep<<<1, 256, 0, stream>>>(wq, g1, b1, bq, wgq, scal);
    k_lnstats<true><<<512, 256, 0, stream>>>(p, wgq, meanb, rstdb, qdotb);
    k_softmax2<<<128, 256, 0, stream>>>(qdotb, meanb, rstdb, scal, ub, Ub);
    k_tpass<<<dim3(4, 4, 32), 256, 0, stream>>>(p, ub, Ub, g1, b1, tb);
    k_ctx2<<<32, 256, 0, stream>>>(tb, wk, bk, ctxb);

    // v = relu(W_v @ LN1(p) + b_v) * ctx  -> bf16
    k_mm<256, 256, 256, 4096, true, 4096, true, S_LNF32, O_RELUCTX_BF16, true>
        <<<dim3(8, 8, 32), 256, 0, stream>>>(
        p, meanb, rstdb, g1, b1, wbase, bvv, ctxb, nullptr, nullptr, vu, 0);
    // p += W_out @ v + b_out
    k_mm<256, 256, 256, 4096, true, 4096, true, S_BF16, O_ADDF32, true>
        <<<dim3(8, 8, 32), 256, 0, stream>>>(
        vu, nullptr, nullptr, nullptr, nullptr, wbase + 65536, out_b + l * Dc,
        nullptr, nullptr, nullptr, p, 0);

    k_lnstats<false><<<512, 256, 0, stream>>>(p, nullptr, meanb, rstdb, nullptr);
    for (int pp = 0; pp < 4; ++pp) {
      // h = lrelu(W1 @ LN2(p) + b1) -> bf16 slice
      k_mm<256, 512, 256, 4096, true, 1024, false, S_LNF32, O_LRELU_BF16, false>
          <<<dim3(8, 4, 32), 256, 0, stream>>>(
          p, meanb, rstdb, g2, b2, wbase + 131072, f1_b + l * FFc,
          nullptr, nullptr, nullptr, hu, pp);
      // p += W2 @ h + b2
      k_mm<512, 256, 512, 1024, false, 4096, true, S_BF16, O_ADDF32, false>
          <<<dim3(8, 2, 32), 256, 0, stream>>>(
          hu, nullptr, nullptr, nullptr, nullptr, wbase + 262144, f2_b + l * Dc,
          nullptr, nullptr, nullptr, p, pp);
    }
  }

  k_lnstats<false><<<512, 256, 0, stream>>>(p, nullptr, meanb, rstdb, nullptr);
  k_bn2pre<<<1, 128, 0, stream>>>(bn2_g, bn2_b, bn2_m, bn2_v, bnscb, bnshb);
  // out = BN2(proj @ LNf(p)) fused with fold
  k_mm<256, 128, 256, 4096, true, 0, false, S_LNF32, O_FOLDBN, true>
      <<<dim3(8, 4, 32), 256, 0, stream>>>(
      p, meanb, rstdb, lnf_g, lnf_b, wf_proj, nullptr,
      nullptr, bnscb, bnshb, out, 0);
}

// Round 6
// 1015.512 us; speedup vs baseline: 5.0255x; 1.2309x over previous
//
#include <hip/hip_runtime.h>

// ---------------------------------------------------------------------------
// MobileViTBlockv2 — fused-chain bf16 MFMA version.
// B=32, C=128, H=W=64, D=256, FF=512, NL=2, PH=PW=2
// p: (B, D, 4, 1024) fp32. Attention chain (v->relu*ctx->out) and FFN chain
// (f1->lrelu->f2) each fused into ONE kernel: phase 1 builds the full
// intermediate for a 64-col tile in LDS (MFMA B-fragment order), phase 2
// consumes it from LDS and accumulates into p. p is read exactly once per
// fused kernel; no intermediate global buffers.
// ---------------------------------------------------------------------------

typedef short  bh8 __attribute__((ext_vector_type(8)));   // 8 bf16 = 4 VGPR
typedef float  f4  __attribute__((ext_vector_type(4)));   // MFMA acc
typedef unsigned short us2 __attribute__((ext_vector_type(2)));
typedef unsigned short us4 __attribute__((ext_vector_type(4)));

constexpr int Bc = 32, Cc = 128, Dc = 256, FFc = 512;
constexpr int NNc = 1024, Sc = 4096;
constexpr float EPSc = 1e-5f;

enum SrcMode { S_LNF32, S_BF16 };
enum OutMode { O_STOREF32, O_FOLDBN };

__device__ __forceinline__ unsigned short f2bf(float f) {
  union { float f; unsigned int u; } v; v.f = f;
  unsigned int u = v.u + 0x7FFFu + ((v.u >> 16) & 1u);
  return (unsigned short)(u >> 16);
}

// ---- weight fp32 -> bf16 MFMA A-fragment order ----------------------------
// (m,k) -> ((kt*(M/16)+mt)*64 + lane)*8 + j ; lane=((k>>3)&3)<<4|(m&15), j=k&7
__global__ __launch_bounds__(256) void k_wconv(
    const float* __restrict__ w, unsigned short* __restrict__ dst,
    int total, int klog2)
{
  int idx = blockIdx.x * 256 + threadIdx.x;
  if (idx >= total) return;
  int K = 1 << klog2;
  int m = idx >> klog2, k = idx & (K - 1);
  int Mt = total >> klog2;
  size_t a = ((size_t)((k >> 5) * (Mt >> 4) + (m >> 4)) * 64
              + (((k >> 3) & 3) << 4) + (m & 15)) * 8 + (k & 7);
  dst[a] = f2bf(w[idx]);
}

// ---- dwconv 3x3 + BN1 + lrelu, 4 pixels/thread, bf16 patch layout ---------
__global__ __launch_bounds__(256) void k_dwconv(
    const float* __restrict__ x, const float* __restrict__ dww,
    const float* __restrict__ g, const float* __restrict__ bb,
    const float* __restrict__ mm, const float* __restrict__ vv,
    unsigned short* __restrict__ y1)
{
  int idx = blockIdx.x * 256 + threadIdx.x;   // (b,c,h,w4)
  int w4 = (idx & 15) * 4;
  int h  = (idx >> 4) & 63;
  int c  = (idx >> 10) & 127;
  int bi = idx >> 17;
  const float* xb = x + (size_t)(bi * 128 + c) * Sc;
  const float* wp = dww + c * 9;
  float acc[4] = {0.f, 0.f, 0.f, 0.f};
  #pragma unroll
  for (int kh = 0; kh < 3; ++kh) {
    int rr = h + kh - 1;
    if (rr < 0 || rr > 63) continue;
    const float* row = xb + rr * 64;
    float4 m4 = *reinterpret_cast<const float4*>(row + w4);
    float v[6];
    v[0] = (w4 > 0)  ? row[w4 - 1] : 0.f;
    v[1] = m4.x; v[2] = m4.y; v[3] = m4.z; v[4] = m4.w;
    v[5] = (w4 < 60) ? row[w4 + 4] : 0.f;
    float w0 = wp[kh * 3], w1 = wp[kh * 3 + 1], w2 = wp[kh * 3 + 2];
    #pragma unroll
    for (int o = 0; o < 4; ++o)
      acc[o] += w0 * v[o] + w1 * v[o + 1] + w2 * v[o + 2];
  }
  float sc = g[c] * rsqrtf(vv[c] + EPSc);
  float sh = bb[c] - mm[c] * sc;
  unsigned short r[4];
  #pragma unroll
  for (int o = 0; o < 4; ++o) {
    float val = acc[o] * sc + sh;
    r[o] = f2bf(val > 0.f ? val : 0.1f * val);
  }
  int ph = h & 1;
  size_t base = (size_t)(bi * 128 + c) * Sc + (h >> 1) * 32 + (w4 >> 1);
  *reinterpret_cast<us2*>(y1 + base + (ph * 2 + 0) * NNc) = (us2){r[0], r[2]};
  *reinterpret_cast<us2*>(y1 + base + (ph * 2 + 1) * NNc) = (us2){r[1], r[3]};
}

// ---- LN stats over D, optionally fused q-dot ------------------------------
template<bool QD>
__global__ __launch_bounds__(256) void k_lnstats(
    const float* __restrict__ p, const float* __restrict__ wgq,
    float* __restrict__ mean_, float* __restrict__ rstd_, float* __restrict__ qdot)
{
  __shared__ float wg_s[256];
  int t = threadIdx.x;
  if (QD) { wg_s[t] = wgq[t]; __syncthreads(); }
  int pos = blockIdx.x * 256 + t;
  int b = pos >> 12, s = pos & 4095;
  const float* base = p + (size_t)b * Dc * Sc + s;
  float sum = 0.f, sq = 0.f, qa = 0.f;
  for (int d = 0; d < Dc; ++d) {
    float v = base[(size_t)d * Sc];
    sum += v; sq += v * v;
    if (QD) qa += v * wg_s[d];
  }
  float m   = sum * (1.f / Dc);
  float var = sq * (1.f / Dc) - m * m;
  mean_[pos] = m;
  rstd_[pos] = rsqrtf(fmaxf(var, 0.f) + EPSc);
  if (QD) qdot[pos] = qa;
}

// ---- per-layer prep: wgq = wq*g, s1 = sum(wq*g), s2 = sum(wq*b)+bq --------
__global__ void k_prep(const float* __restrict__ wq, const float* __restrict__ lng,
                       const float* __restrict__ lnb, const float* __restrict__ qb,
                       float* __restrict__ wgq, float* __restrict__ scal)
{
  int t = threadIdx.x, lane = t & 63, wv = t >> 6;
  float w = wq[t];
  float a = w * lng[t], c2 = w * lnb[t];
  wgq[t] = a;
  __shared__ float ra[4], rb[4];
  #pragma unroll
  for (int off = 32; off > 0; off >>= 1) { a += __shfl_xor(a, off); c2 += __shfl_xor(c2, off); }
  if (lane == 0) { ra[wv] = a; rb[wv] = c2; }
  __syncthreads();
  if (t == 0) {
    scal[0] = ra[0] + ra[1] + ra[2] + ra[3];
    scal[1] = rb[0] + rb[1] + rb[2] + rb[3] + qb[0];
  }
}

// ---- softmax over N from qdot/stats; emits u[n]=rs*s and U=sum(m*u) -------
__global__ __launch_bounds__(256) void k_softmax2(
    const float* __restrict__ qdot, const float* __restrict__ mean_,
    const float* __restrict__ rstd_, const float* __restrict__ scal,
    float* __restrict__ ub, float* __restrict__ Ub)
{
  int bp = blockIdx.x, b = bp >> 2, pp = bp & 3;
  int t = threadIdx.x, lane = t & 63, wv = t >> 6;
  __shared__ float r3[4], r4[4];
  float s1 = scal[0], s2 = scal[1];
  int pos0 = b * Sc + pp * NNc;
  float q[4], m_r[4], rs_r[4];
  float mx = -3.4e38f;
  #pragma unroll
  for (int i = 0; i < 4; ++i) {
    int pos = pos0 + t + i * 256;
    m_r[i] = mean_[pos]; rs_r[i] = rstd_[pos];
    q[i] = rs_r[i] * qdot[pos] - m_r[i] * rs_r[i] * s1 + s2;
    mx = fmaxf(mx, q[i]);
  }
  #pragma unroll
  for (int off = 32; off > 0; off >>= 1) mx = fmaxf(mx, __shfl_xor(mx, off));
  if (lane == 0) r3[wv] = mx;
  __syncthreads();
  mx = fmaxf(fmaxf(r3[0], r3[1]), fmaxf(r3[2], r3[3]));
  float sum = 0.f;
  #pragma unroll
  for (int i = 0; i < 4; ++i) { q[i] = __expf(q[i] - mx); sum += q[i]; }
  #pragma unroll
  for (int off = 32; off > 0; off >>= 1) sum += __shfl_xor(sum, off);
  if (lane == 0) r4[wv] = sum;
  __syncthreads();
  float inv = 1.f / (r4[0] + r4[1] + r4[2] + r4[3]);
  float pU = 0.f;
  #pragma unroll
  for (int i = 0; i < 4; ++i) {
    float un = rs_r[i] * q[i] * inv;
    ub[(size_t)bp * NNc + t + i * 256] = un;
    pU += m_r[i] * un;
  }
  #pragma unroll
  for (int off = 32; off > 0; off >>= 1) pU += __shfl_xor(pU, off);
  if (lane == 0) r3[wv] = pU;
  __syncthreads();
  if (t == 0) Ub[bp] = r3[0] + r3[1] + r3[2] + r3[3];
}

// ---- t_c = g_c*(sum_n p[c,n]*u[n] - U) + b_c ------------------------------
__global__ __launch_bounds__(256) void k_tpass(
    const float* __restrict__ p, const float* __restrict__ ub,
    const float* __restrict__ Ub, const float* __restrict__ lng,
    const float* __restrict__ lnb, float* __restrict__ tb)
{
  int cs = blockIdx.x, pp = blockIdx.y, b = blockIdx.z;
  int bp = b * 4 + pp;
  int t = threadIdx.x, lane = t & 63, wv = t >> 6;
  __shared__ float u_s[1024];
  for (int i = t; i < 1024; i += 256) u_s[i] = ub[(size_t)bp * NNc + i];
  __syncthreads();
  float U = Ub[bp];
  const float* pb = p + (size_t)b * Dc * Sc + pp * NNc;
  for (int i = 0; i < 16; ++i) {
    int c = cs * 64 + wv * 16 + i;
    const float* row = pb + (size_t)c * Sc;
    float sm = 0.f;
    #pragma unroll
    for (int j = 0; j < 16; ++j) { int n = lane + 64 * j; sm += row[n] * u_s[n]; }
    #pragma unroll
    for (int off = 32; off > 0; off >>= 1) sm += __shfl_xor(sm, off);
    if (lane == 0) tb[(size_t)bp * Dc + c] = lng[c] * (sm - U) + lnb[c];
  }
}

// ---- ctx[b,d,pp] = wk_row_d . t[b,pp,:] + bk_d ----------------------------
__global__ __launch_bounds__(256) void k_ctx2(
    const float* __restrict__ tb, const float* __restrict__ wk,
    const float* __restrict__ bk, float* __restrict__ ctxb)
{
  int b = blockIdx.x, d = threadIdx.x;
  __shared__ float ts[4][256];
  for (int i = threadIdx.x; i < 1024; i += 256) ts[i >> 8][i & 255] = tb[(size_t)b * 1024 + i];
  __syncthreads();
  const float* wrow = wk + (size_t)d * 256;
  float bkd = bk[d];
  float accp[4] = {0.f, 0.f, 0.f, 0.f};
  for (int c = 0; c < 256; c += 4) {
    float4 wv = *reinterpret_cast<const float4*>(wrow + c);
    #pragma unroll
    for (int pp = 0; pp < 4; ++pp)
      accp[pp] += wv.x * ts[pp][c] + wv.y * ts[pp][c + 1]
                + wv.z * ts[pp][c + 2] + wv.w * ts[pp][c + 3];
  }
  #pragma unroll
  for (int pp = 0; pp < 4; ++pp)
    ctxb[((size_t)(b * 256 + d)) * 4 + pp] = accp[pp] + bkd;
}

__global__ void k_bn2pre(const float* __restrict__ g, const float* __restrict__ bb,
                         const float* __restrict__ mm, const float* __restrict__ vv,
                         float* __restrict__ sc, float* __restrict__ sh)
{
  int c = threadIdx.x;
  if (c < Cc) {
    float s = g[c] * rsqrtf(vv[c] + EPSc);
    sc[c] = s;
    sh[c] = bb[c] - mm[c] * s;
  }
}

// ---------------------------------------------------------------------------
// Fused chain kernel: one (b, pp, 64-col n-tile) per block, 4 waves.
// Phase 1: I = act(W1 @ LN(p) + b1) [* ctx if ATTN], full M1 rows, K=256.
//          Result written to LDS in MFMA B-fragment order.
// Phase 2: p += W2 @ I + b2   (M2=256, K=M1), I read from LDS.
// ---------------------------------------------------------------------------
template<int M1, bool ATTN>
__global__ __launch_bounds__(256) void k_fused(
    const float* __restrict__ p,
    const float* __restrict__ mean_, const float* __restrict__ rstd_,
    const float* __restrict__ lng, const float* __restrict__ lnb,
    const unsigned short* __restrict__ wf1, const float* __restrict__ b1,
    const float* __restrict__ ctxp,
    const unsigned short* __restrict__ wf2, const float* __restrict__ b2,
    float* __restrict__ dst)
{
  constexpr int ACC1 = M1 / 64;          // row-tiles per wave, phase 1
  int t = threadIdx.x;
  int wv = t >> 6, lane = t & 63;
  int q = lane >> 4, ln16 = lane & 15;
  int nt = blockIdx.x, pp = blockIdx.y, b = blockIdx.z;
  int n0 = nt * 64;

  __shared__ unsigned int Alds[64 * 20];          // 5 KB staging (32k x 64n)
  __shared__ unsigned short Frag[M1 * 64];        // intermediate, B-frag order
  __shared__ float m_s[64], rs_s[64];
  __shared__ float ctx_s[256];

  if (t < 64) {
    int pos = b * Sc + pp * NNc + n0 + t;
    m_s[t]  = mean_[pos];
    rs_s[t] = rstd_[pos];
  }
  if (ATTN) ctx_s[t] = ctxp[(size_t)(b * Dc + t) * 4 + pp];

  f4 acc[ACC1][4];
  #pragma unroll
  for (int i = 0; i < ACC1; ++i)
    #pragma unroll
    for (int j = 0; j < 4; ++j) acc[i][j] = (f4){0.f, 0.f, 0.f, 0.f};

  size_t pbase = (size_t)b * Dc * Sc + pp * NNc + n0;

  // ---- phase 1: I = W1 @ LN(p) ----
  for (int kc = 0; kc < 256; kc += 32) {
    bh8 aw[ACC1];
    #pragma unroll
    for (int tm = 0; tm < ACC1; ++tm)
      aw[tm] = *(const bh8*)(wf1 + ((size_t)((kc >> 5) * (M1 >> 4) + wv * ACC1 + tm) * 64 + lane) * 8);
    __syncthreads();
    #pragma unroll
    for (int it = 0; it < 4; ++it) {
      int i = it * 256 + t;
      int kp = i >> 6, n_l = i & 63;
      int k0 = kc + kp * 2;
      float a0 = p[pbase + (size_t)k0 * Sc + n_l];
      float a1 = p[pbase + (size_t)(k0 + 1) * Sc + n_l];
      float ms = m_s[n_l], rs = rs_s[n_l];
      a0 = (a0 - ms) * rs * lng[k0] + lnb[k0];
      a1 = (a1 - ms) * rs * lng[k0 + 1] + lnb[k0 + 1];
      Alds[n_l * 20 + kp] = (unsigned int)f2bf(a0) | ((unsigned int)f2bf(a1) << 16);
    }
    __syncthreads();
    const unsigned short* al = (const unsigned short*)Alds;
    #pragma unroll
    for (int tn = 0; tn < 4; ++tn) {
      bh8 bwf = *(const bh8*)(al + (tn * 16 + ln16) * 40 + q * 8);
      #pragma unroll
      for (int tm = 0; tm < ACC1; ++tm)
        acc[tm][tn] = __builtin_amdgcn_mfma_f32_16x16x32_bf16(aw[tm], bwf, acc[tm][tn], 0, 0, 0);
    }
  }

  // ---- phase 1 epilogue: act + write Frag (B-frag order) ----
  __syncthreads();
  #pragma unroll
  for (int tm = 0; tm < ACC1; ++tm) {
    int row0 = wv * (M1 / 4) + tm * 16 + q * 4;
    float bia[4], cxv[4];
    #pragma unroll
    for (int r = 0; r < 4; ++r) {
      bia[r] = b1[row0 + r];
      if (ATTN) cxv[r] = ctx_s[row0 + r];
    }
    int kt  = row0 >> 5;
    int sub = (row0 >> 3) & 3;
    int jo  = row0 & 7;
    #pragma unroll
    for (int tn = 0; tn < 4; ++tn) {
      int cl = tn * 16 + ln16;
      us4 pk;
      #pragma unroll
      for (int r = 0; r < 4; ++r) {
        float v = acc[tm][tn][r] + bia[r];
        if (ATTN) v = fmaxf(v, 0.f) * cxv[r];
        else      v = v > 0.f ? v : 0.1f * v;
        pk[r] = f2bf(v);
      }
      *reinterpret_cast<us4*>(Frag + (((kt * 4 + (cl >> 4)) * 64 + (sub << 4 | (cl & 15))) * 8 + jo)) = pk;
    }
  }
  __syncthreads();

  // ---- phase 2: p += W2 @ I ----
  f4 acc2[4][4];
  #pragma unroll
  for (int i = 0; i < 4; ++i)
    #pragma unroll
    for (int j = 0; j < 4; ++j) acc2[i][j] = (f4){0.f, 0.f, 0.f, 0.f};

  for (int kc = 0; kc < M1; kc += 32) {
    bh8 aw2[4];
    #pragma unroll
    for (int tm = 0; tm < 4; ++tm)
      aw2[tm] = *(const bh8*)(wf2 + ((size_t)((kc >> 5) * 16 + wv * 4 + tm) * 64 + lane) * 8);
    #pragma unroll
    for (int tn = 0; tn < 4; ++tn) {
      bh8 bwf = *(const bh8*)(Frag + ((kc >> 5) * 4 + tn) * 512 + lane * 8);
      #pragma unroll
      for (int tm = 0; tm < 4; ++tm)
        acc2[tm][tn] = __builtin_amdgcn_mfma_f32_16x16x32_bf16(aw2[tm], bwf, acc2[tm][tn], 0, 0, 0);
    }
  }

  #pragma unroll
  for (int tm = 0; tm < 4; ++tm) {
    #pragma unroll
    for (int r = 0; r < 4; ++r) {
      int row = wv * 64 + tm * 16 + q * 4 + r;
      float bv = b2[row];
      #pragma unroll
      for (int tn = 0; tn < 4; ++tn) {
        int col = n0 + tn * 16 + ln16;
        size_t da = (size_t)(b * Dc + row) * Sc + pp * NNc + col;
        dst[da] += acc2[tm][tn][r] + bv;
      }
    }
  }
}

// ---------------------------------------------------------------------------
// Standalone MFMA GEMM (used for c1 and proj). Same as R4.
// ---------------------------------------------------------------------------
template<int KTOT, int MTOT, int SRCCH, int SSTR, bool SPP,
         SrcMode SM, OutMode OM>
__global__ __launch_bounds__(256) void k_mm(
    const void* __restrict__ src,
    const float* __restrict__ mean_, const float* __restrict__ rstd_,
    const float* __restrict__ lng, const float* __restrict__ lnb,
    const unsigned short* __restrict__ wf, const float* __restrict__ bias,
    const float* __restrict__ bnsc, const float* __restrict__ bnsh,
    void* __restrict__ dst)
{
  int t = threadIdx.x;
  int wv = t >> 6, lane = t & 63;
  int wm = wv & 1, wn = wv >> 1;
  int q = lane >> 4, ln16 = lane & 15;
  int nb = blockIdx.x, b = blockIdx.z;
  int pp = blockIdx.y & 3, mb = blockIdx.y >> 2;
  int n0  = nb * 128;
  int MB0 = mb * 128;

  __shared__ unsigned int Alds[128 * 20];
  __shared__ float m_s[128], rs_s[128];

  if (SM == S_LNF32 && t < 128) {
    int pos = b * Sc + pp * NNc + n0 + t;
    m_s[t]  = mean_[pos];
    rs_s[t] = rstd_[pos];
  }

  f4 acc[4][4];
  #pragma unroll
  for (int i = 0; i < 4; ++i)
    #pragma unroll
    for (int j = 0; j < 4; ++j) acc[i][j] = (f4){0.f, 0.f, 0.f, 0.f};

  size_t sbase = (size_t)b * SRCCH * SSTR + pp * NNc + n0;
  int mtb = (MB0 >> 4) + wm * 4;

  for (int kc = 0; kc < KTOT; kc += 32) {
    bh8 aw[4];
    #pragma unroll
    for (int tm = 0; tm < 4; ++tm)
      aw[tm] = *(const bh8*)(wf + ((size_t)((kc >> 5) * (MTOT >> 4) + mtb + tm) * 64 + lane) * 8);
    __syncthreads();
    #pragma unroll
    for (int it = 0; it < 8; ++it) {
      int n_l = (t & 63) + (it & 1) * 64;
      int kp  = (t >> 6) + (it >> 1) * 4;
      int k0  = kc + kp * 2;
      unsigned int pk;
      if (SM == S_LNF32) {
        const float* sp = (const float*)src;
        float a0 = sp[sbase + (size_t)k0 * SSTR + n_l];
        float a1 = sp[sbase + (size_t)(k0 + 1) * SSTR + n_l];
        float ms = m_s[n_l], rs = rs_s[n_l];
        a0 = (a0 - ms) * rs * lng[k0] + lnb[k0];
        a1 = (a1 - ms) * rs * lng[k0 + 1] + lnb[k0 + 1];
        pk = (unsigned int)f2bf(a0) | ((unsigned int)f2bf(a1) << 16);
      } else {
        const unsigned short* sp = (const unsigned short*)src;
        unsigned int u0 = sp[sbase + (size_t)k0 * SSTR + n_l];
        unsigned int u1 = sp[sbase + (size_t)(k0 + 1) * SSTR + n_l];
        pk = u0 | (u1 << 16);
      }
      Alds[n_l * 20 + kp] = pk;
    }
    __syncthreads();
    const unsigned short* al = (const unsigned short*)Alds;
    #pragma unroll
    for (int tn = 0; tn < 4; ++tn) {
      int nrow = wn * 64 + tn * 16 + ln16;
      bh8 bwf = *(const bh8*)(al + nrow * 40 + q * 8);
      #pragma unroll
      for (int tm = 0; tm < 4; ++tm)
        acc[tm][tn] = __builtin_amdgcn_mfma_f32_16x16x32_bf16(aw[tm], bwf, acc[tm][tn], 0, 0, 0);
    }
  }

  #pragma unroll
  for (int tm = 0; tm < 4; ++tm) {
    #pragma unroll
    for (int r = 0; r < 4; ++r) {
      int row = MB0 + wm * 64 + tm * 16 + q * 4 + r;
      float scv = 0.f, shv = 0.f, bv = 0.f;
      if (OM == O_FOLDBN) { scv = bnsc[row]; shv = bnsh[row]; }
      else                { bv = bias[row]; }
      #pragma unroll
      for (int tn = 0; tn < 4; ++tn) {
        int col = n0 + wn * 64 + tn * 16 + ln16;
        float v = acc[tm][tn][r];
        if (OM == O_FOLDBN) {
          int hh = 2 * (col >> 5) + (pp >> 1), ww = 2 * (col & 31) + (pp & 1);
          ((float*)dst)[((size_t)(b * Cc + row)) * Sc + hh * 64 + ww] = v * scv + shv;
        } else {
          ((float*)dst)[(size_t)(b * MTOT + row) * Sc + pp * NNc + col] = v + bv;
        }
      }
    }
  }
}

// ---------------------------------------------------------------------------
extern "C" void kernel_launch(void* const* d_in, const int* in_sizes, int n_in,
                              void* d_out, int out_size, void* d_ws, size_t ws_size,
                              hipStream_t stream)
{
  const float* x     = (const float*)d_in[0];
  const float* dw_w  = (const float*)d_in[1];
  const float* bn1_g = (const float*)d_in[2];
  const float* bn1_b = (const float*)d_in[3];
  const float* bn1_m = (const float*)d_in[4];
  const float* bn1_v = (const float*)d_in[5];
  const float* c1_w  = (const float*)d_in[6];
  const float* c1_b  = (const float*)d_in[7];
  const float* ln1_g = (const float*)d_in[8];
  const float* ln1_b = (const float*)d_in[9];
  const float* qkv_w = (const float*)d_in[10];
  const float* qkv_b = (const float*)d_in[11];
  const float* out_w = (const float*)d_in[12];
  const float* out_b = (const float*)d_in[13];
  const float* ln2_g = (const float*)d_in[14];
  const float* ln2_b = (const float*)d_in[15];
  const float* f1_w  = (const float*)d_in[16];
  const float* f1_b  = (const float*)d_in[17];
  const float* f2_w  = (const float*)d_in[18];
  const float* f2_b  = (const float*)d_in[19];
  const float* lnf_g = (const float*)d_in[20];
  const float* lnf_b = (const float*)d_in[21];
  const float* projw = (const float*)d_in[22];
  const float* bn2_g = (const float*)d_in[23];
  const float* bn2_b = (const float*)d_in[24];
  const float* bn2_m = (const float*)d_in[25];
  const float* bn2_v = (const float*)d_in[26];
  float* out = (float*)d_out;

  // ---- workspace (~172 MB) ----
  float* ws    = (float*)d_ws;
  float* p     = ws;                                       // 33,554,432 f
  float* reg   = p + (size_t)33554432;                     // 8,388,608 f (y1 bf16)
  unsigned short* y1u = (unsigned short*)reg;
  float* meanb = reg   + (size_t)8388608;
  float* rstdb = meanb + 131072;
  float* qdotb = rstdb + 131072;
  float* ub    = qdotb + 131072;
  float* Ub    = ub    + 131072;                           // 128
  float* tb    = Ub    + 128;                              // 32768
  float* ctxb  = tb    + 32768;                            // 32768
  float* wgq   = ctxb  + 32768;                            // 256
  float* scal  = wgq   + 256;                              // 16
  float* bnscb = scal  + 16;                               // 128
  float* bnshb = bnscb + 128;                              // 128
  unsigned short* wfb = (unsigned short*)(bnshb + 128);
  unsigned short* wf_c1   = wfb;                           // 32768
  unsigned short* wf_v0   = wfb + 32768;                   // per-l stride 393216
  unsigned short* wf_proj = wfb + 32768 + 2 * 393216;      // 32768

  // ---- weight conversion ----
  k_wconv<<<128, 256, 0, stream>>>(c1_w, wf_c1, 256 * 128, 7);
  for (int l = 0; l < 2; ++l) {
    const float* wvp = qkv_w + ((size_t)l * 513 + 257) * Dc;
    unsigned short* base = wf_v0 + (size_t)l * 393216;
    k_wconv<<<256, 256, 0, stream>>>(wvp, base, 256 * 256, 8);
    k_wconv<<<256, 256, 0, stream>>>(out_w + (size_t)l * Dc * Dc, base + 65536, 256 * 256, 8);
    k_wconv<<<512, 256, 0, stream>>>(f1_w + (size_t)l * FFc * Dc, base + 131072, 512 * 256, 8);
    k_wconv<<<512, 256, 0, stream>>>(f2_w + (size_t)l * Dc * FFc, base + 262144, 256 * 512, 9);
  }
  k_wconv<<<128, 256, 0, stream>>>(projw, wf_proj, 128 * 256, 8);

  // ---- 1) dwconv + BN1 + lrelu -> y1 bf16 (patch layout) ----
  k_dwconv<<<16384, 256, 0, stream>>>(x, dw_w, bn1_g, bn1_b, bn1_m, bn1_v, y1u);

  // ---- 2) c1: p = W_c1 @ y1 + b ----
  k_mm<128, 256, 128, 4096, true, S_BF16, O_STOREF32>
      <<<dim3(8, 8, 32), 256, 0, stream>>>(
      y1u, nullptr, nullptr, nullptr, nullptr, wf_c1, c1_b, nullptr, nullptr, p);

  for (int l = 0; l < 2; ++l) {
    const float* g1 = ln1_g + l * Dc; const float* b1 = ln1_b + l * Dc;
    const float* g2 = ln2_g + l * Dc; const float* b2 = ln2_b + l * Dc;
    const float* wq = qkv_w + (size_t)l * 513 * Dc;
    const float* wk = qkv_w + ((size_t)l * 513 + 1) * Dc;
    const float* bq = qkv_b + l * 513;
    const float* bk = qkv_b + l * 513 + 1;
    const float* bvv = qkv_b + l * 513 + 257;
    unsigned short* wbase = wf_v0 + (size_t)l * 393216;

    k_prep<<<1, 256, 0, stream>>>(wq, g1, b1, bq, wgq, scal);
    k_lnstats<true><<<512, 256, 0, stream>>>(p, wgq, meanb, rstdb, qdotb);
    k_softmax2<<<128, 256, 0, stream>>>(qdotb, meanb, rstdb, scal, ub, Ub);
    k_tpass<<<dim3(4, 4, 32), 256, 0, stream>>>(p, ub, Ub, g1, b1, tb);
    k_ctx2<<<32, 256, 0, stream>>>(tb, wk, bk, ctxb);

    // fused attention: p += W_out @ (relu(W_v @ LN1(p) + b_v) * ctx) + b_out
    k_fused<256, true><<<dim3(16, 4, 32), 256, 0, stream>>>(
        p, meanb, rstdb, g1, b1, wbase, bvv, ctxb,
        wbase + 65536, out_b + l * Dc, p);

    k_lnstats<false><<<512, 256, 0, stream>>>(p, nullptr, meanb, rstdb, nullptr);
    // fused FFN: p += W2 @ lrelu(W1 @ LN2(p) + b1) + b2
    k_fused<512, false><<<dim3(16, 4, 32), 256, 0, stream>>>(
        p, meanb, rstdb, g2, b2, wbase + 131072, f1_b + l * FFc, nullptr,
        wbase + 262144, f2_b + l * Dc, p);
  }

  k_lnstats<false><<<512, 256, 0, stream>>>(p, nullptr, meanb, rstdb, nullptr);
  k_bn2pre<<<1, 128, 0, stream>>>(bn2_g, bn2_b, bn2_m, bn2_v, bnscb, bnshb);
  // out = BN2(proj @ LNf(p)) fused with fold
  k_mm<256, 128, 256, 4096, true, S_LNF32, O_FOLDBN>
      <<<dim3(8, 4, 32), 256, 0, stream>>>(
      p, meanb, rstdb, lnf_g, lnf_b, wf_proj, nullptr, bnscb, bnshb, out);
}